// Round 1
// 687.366 us; speedup vs baseline: 1.0074x; 1.0074x over previous
//
#include <hip/hip_runtime.h>
#include <cstdint>
#include <cmath>

#define H 32
#define HKV 8
#define DD 128
#define HID 4096
#define II 12288
#define SS 8192
#define EPSF 1e-6f
#define CS 256
#define NC (SS / CS) /* 32 */

typedef float f4 __attribute__((ext_vector_type(4)));

__device__ __forceinline__ float wave_reduce_sum(float v) {
#pragma unroll
    for (int off = 32; off; off >>= 1) v += __shfl_down(v, off, 64);
    return v;
}

__device__ __forceinline__ f4 ntload(const f4* p) {
    return __builtin_nontemporal_load(p);
}

// ---------------- front: fused {RMSNorm + QKV GEMV} + {KV bulk copy} ---------
// grid 5632 x 256.
//   b in [0,1536):   4 waves x 1 row of the 6144-row QKV GEMV (weights via nt).
//   b in [1536,5632): KV cache copy, 4 float4 per thread. REGULAR (cached)
//                     loads/stores: kc/vc (67 MB) + out rows stay L3-resident
//                     (weights stream nt so they don't evict them); attn then
//                     reads hot lines, and next timed iteration re-reads warm.
__global__ __launch_bounds__(256) void front(const float* __restrict__ Wq,
                                             const float* __restrict__ Wk,
                                             const float* __restrict__ Wv,
                                             const float* __restrict__ x,
                                             const float* __restrict__ ln1,
                                             const float* __restrict__ kc,
                                             const float* __restrict__ vc,
                                             float* __restrict__ q,
                                             float* __restrict__ k,
                                             float* __restrict__ v,
                                             float* __restrict__ ok,
                                             float* __restrict__ ov) {
    __shared__ float red[4];
    int b = blockIdx.x;
    int t = threadIdx.x;
    if (b >= 1536) {  // ---- KV copy branch (whole-block uniform) ----
        int idx = b - 1536;
        const f4* src;
        f4* dst;
        if (idx < 2048) { src = (const f4*)kc; dst = (f4*)ok; }
        else            { src = (const f4*)vc; dst = (f4*)ov; idx -= 2048; }
        size_t base = (size_t)idx * 1024 + t;
#pragma unroll
        for (int j = 0; j < 4; j++) {
            size_t i = base + (size_t)j * 256;
            dst[i] = src[i];
        }
        return;
    }
    // ---- fused RMSNorm + QKV GEMV branch ----
    int wave = t >> 6, lane = t & 63;
    const f4* x4 = (const f4*)x;
    const f4* l4 = (const f4*)ln1;
    float ss = 0.f;
#pragma unroll
    for (int i = 0; i < 4; i++) {
        f4 a = x4[t + i * 256];
        ss += a.x * a.x + a.y * a.y + a.z * a.z + a.w * a.w;
    }
    ss = wave_reduce_sum(ss);
    if (lane == 0) red[wave] = ss;
    __syncthreads();
    float r = rsqrtf((red[0] + red[1] + red[2] + red[3]) * (1.f / (float)HID) + EPSF);

    int row = b * 4 + wave;
    const float* wrow;
    float* out;
    int ro;
    if (row < 4096)      { wrow = Wq + (size_t)row * HID;          out = q; ro = row; }
    else if (row < 5120) { wrow = Wk + (size_t)(row - 4096) * HID; out = k; ro = row - 4096; }
    else                 { wrow = Wv + (size_t)(row - 5120) * HID; out = v; ro = row - 5120; }
    const f4* w4 = (const f4*)wrow;
    float acc = 0.f;
#pragma unroll
    for (int ii = 0; ii < 16; ii++) {
        int i = lane + ii * 64;
        f4 a = ntload(w4 + i);
        f4 b2 = x4[i];
        f4 c = l4[i];
        acc += a.x * b2.x * c.x + a.y * b2.y * c.y + a.z * b2.z * c.z + a.w * b2.w * c.w;
    }
    acc = wave_reduce_sum(acc);
    if (lane == 0) out[ro] = acc * r;
}

// ---------------- Attention partials, with in-block q/k norm+RoPE ------------
// grid (H, NC) x 256. rope_insert kernel is GONE: each active block redundantly
// normalizes+ropes its q head (t<128) and, in the chunk containing pos, its
// kv head's new k row (t>=128) + loads the v row; the (h&3)==0 block of that
// chunk writes the new rows into out_k/out_v. Raw q/k/v stay untouched in ws.
__global__ __launch_bounds__(256) void attn_partial(const float* __restrict__ qraw,
                                                    const float* __restrict__ kraw,
                                                    const float* __restrict__ vraw,
                                                    float* __restrict__ ok,
                                                    float* __restrict__ ov,
                                                    const float* __restrict__ cv,
                                                    const float* __restrict__ sv,
                                                    const float* __restrict__ qw,
                                                    const float* __restrict__ kw,
                                                    const float* __restrict__ position,
                                                    float* __restrict__ pm,
                                                    float* __restrict__ pl,
                                                    float* __restrict__ po) {
    int h = blockIdx.x, c = blockIdx.y, t = threadIdx.x;
    int pos = (int)position[0];
    if (c * CS > pos) {  // fully-masked chunk
        if (t == 0) { pm[h * NC + c] = -INFINITY; pl[h * NC + c] = 0.f; }
        return;
    }
    int kvh = h >> 2;
    int pc = pos / CS;
    bool haspos = (c == pc);

    __shared__ float red[256];
    __shared__ float sh[256];
    __shared__ float qs[DD];
    __shared__ float ksh[DD];
    __shared__ float vsh[DD];
    __shared__ float pvs[CS];

    // two independent 128-wide sum-of-squares reductions (q in red[0:128],
    // new-k in red[128:256])
    float val = 0.f;
    if (t < DD)            val = qraw[(size_t)h * DD + t];
    else if (haspos)       val = kraw[(size_t)kvh * DD + (t - DD)];
    red[t] = val * val;
    __syncthreads();
#pragma unroll
    for (int off = 64; off; off >>= 1) {
        if ((t & 127) < off) red[t] += red[t + off];
        __syncthreads();
    }
    float rq = rsqrtf(red[0] * (1.f / (float)DD) + EPSF);
    float rk = rsqrtf(red[DD] * (1.f / (float)DD) + EPSF);
    if (t < DD)           sh[t] = val * rq * qw[t];
    else if (haspos)      sh[t] = val * rk * kw[t - DD];
    __syncthreads();
    if (t < DD) {
        float other = (t < 64) ? -sh[t + 64] : sh[t - 64];
        qs[t] = sh[t] * cv[t] + other * sv[t];
        if (haspos) vsh[t] = vraw[(size_t)kvh * DD + t];
    } else if (haspos) {
        int d = t - DD;
        float other = (d < 64) ? -sh[DD + d + 64] : sh[DD + d - 64];
        ksh[d] = sh[t] * cv[d] + other * sv[d];
    }
    __syncthreads();
    // one designated block per kv head writes the new cache rows
    if (haspos && (h & 3) == 0 && t < DD) {
        ok[((size_t)kvh * SS + pos) * DD + t] = ksh[t];
        ov[((size_t)kvh * SS + pos) * DD + t] = vsh[t];
    }

    // scores
    int s = c * CS + t;
    float score = -INFINITY;
    if (s <= pos) {
        const f4* q4 = (const f4*)qs;
        float acc = 0.f;
        if (s < pos) {
            const f4* kr = (const f4*)(ok + ((size_t)kvh * SS + s) * DD);
#pragma unroll
            for (int i = 0; i < DD / 4; i++) {
                f4 a = kr[i], bq = q4[i];
                acc += a.x * bq.x + a.y * bq.y + a.z * bq.z + a.w * bq.w;
            }
        } else {  // s == pos: use the freshly-computed row in LDS
            const f4* kr = (const f4*)ksh;
#pragma unroll
            for (int i = 0; i < DD / 4; i++) {
                f4 a = kr[i], bq = q4[i];
                acc += a.x * bq.x + a.y * bq.y + a.z * bq.z + a.w * bq.w;
            }
        }
        score = acc * 0.08838834764831845f;  // 1/sqrt(128)
    }
    red[t] = score;
    __syncthreads();
#pragma unroll
    for (int off = 128; off; off >>= 1) {
        if (t < off) red[t] = fmaxf(red[t], red[t + off]);
        __syncthreads();
    }
    float m = red[0];
    __syncthreads();
    float p = (score == -INFINITY) ? 0.f : expf(score - m);
    pvs[t] = p;
    red[t] = p;
    __syncthreads();
#pragma unroll
    for (int off = 128; off; off >>= 1) {
        if (t < off) red[t] += red[t + off];
        __syncthreads();
    }
    float l = red[0];
    int jend = pos + 1 - c * CS;
    if (jend > CS) jend = CS;
    int jlim = haspos ? jend - 1 : jend;  // last row of pos-chunk comes from LDS
    if (t < DD) {
        float acc = 0.f;
        for (int j = 0; j < jlim; j++) {
            acc += pvs[j] * ov[((size_t)kvh * SS + (size_t)(c * CS + j)) * DD + t];
        }
        if (haspos) acc += pvs[jend - 1] * vsh[t];
        po[((size_t)h * NC + c) * DD + t] = acc;
    }
    if (t == 0) {
        pm[h * NC + c] = m;
        pl[h * NC + c] = l;
    }
}

// ---------------- Attention combine (H blocks x 128 threads) -----------------
__global__ __launch_bounds__(128) void attn_combine(const float* __restrict__ pm,
                                                    const float* __restrict__ pl,
                                                    const float* __restrict__ po,
                                                    float* __restrict__ ao) {
    int h = blockIdx.x, d = threadIdx.x;
    float M = -INFINITY;
    for (int c = 0; c < NC; c++) M = fmaxf(M, pm[h * NC + c]);
    float L = 0.f, acc = 0.f;
    for (int c = 0; c < NC; c++) {
        float mm = pm[h * NC + c];
        if (mm == -INFINITY) continue;
        float wgt = expf(mm - M);
        L += wgt * pl[h * NC + c];
        acc += wgt * po[((size_t)h * NC + c) * DD + d];
    }
    ao[h * DD + d] = acc / L;
}

// ---------------- Wo GEMV + residual (wave-per-row, 4096 rows) ---------------
__global__ __launch_bounds__(256) void gemv_wo(const float* __restrict__ W,
                                               const float* __restrict__ xin,
                                               const float* __restrict__ resid,
                                               float* __restrict__ out) {
    int wave = threadIdx.x >> 6, lane = threadIdx.x & 63;
    int row = blockIdx.x * 4 + wave;
    const f4* w4 = (const f4*)(W + (size_t)row * HID);
    const f4* x4 = (const f4*)xin;
    float acc = 0.f;
#pragma unroll
    for (int ii = 0; ii < 16; ii++) {
        int i = lane + ii * 64;
        f4 a = ntload(w4 + i);
        f4 b = x4[i];
        acc += a.x * b.x + a.y * b.y + a.z * b.z + a.w * b.w;
    }
    acc = wave_reduce_sum(acc);
    if (lane == 0) out[row] = resid[row] + acc;
}

// ---------------- Fused RMSNorm + Gate/Up GEMV + SiLU (12288 rows) -----------
__global__ __launch_bounds__(256) void gemv_gateup(const float* __restrict__ Wg,
                                                   const float* __restrict__ Wu,
                                                   const float* __restrict__ h1,
                                                   const float* __restrict__ ln2,
                                                   float* __restrict__ m) {
    __shared__ float red[4];
    int t = threadIdx.x;
    int wave = t >> 6, lane = t & 63;
    const f4* x4 = (const f4*)h1;
    const f4* l4 = (const f4*)ln2;
    float ss = 0.f;
#pragma unroll
    for (int i = 0; i < 4; i++) {
        f4 a = x4[t + i * 256];
        ss += a.x * a.x + a.y * a.y + a.z * a.z + a.w * a.w;
    }
    ss = wave_reduce_sum(ss);
    if (lane == 0) red[wave] = ss;
    __syncthreads();
    float r = rsqrtf((red[0] + red[1] + red[2] + red[3]) * (1.f / (float)HID) + EPSF);

    int row = blockIdx.x * 4 + wave;
    const f4* g4 = (const f4*)(Wg + (size_t)row * HID);
    const f4* u4 = (const f4*)(Wu + (size_t)row * HID);
    float accg = 0.f, accu = 0.f;
#pragma unroll
    for (int ii = 0; ii < 16; ii++) {
        int i = lane + ii * 64;
        f4 b = x4[i];
        f4 c = l4[i];
        f4 hb; hb.x = b.x * c.x; hb.y = b.y * c.y; hb.z = b.z * c.z; hb.w = b.w * c.w;
        f4 a = ntload(g4 + i);
        accg += a.x * hb.x + a.y * hb.y + a.z * hb.z + a.w * hb.w;
        f4 u = ntload(u4 + i);
        accu += u.x * hb.x + u.y * hb.y + u.z * hb.z + u.w * hb.w;
    }
    accg = wave_reduce_sum(accg);
    accu = wave_reduce_sum(accu);
    if (lane == 0) {
        float g = accg * r, uu = accu * r;
        m[row] = (g / (1.f + expf(-g))) * uu;  // silu(g) * u
    }
}

// ---------------- Down GEMV + residual (4096 rows, K=12288) ------------------
__global__ __launch_bounds__(256) void gemv_down(const float* __restrict__ Wd,
                                                 const float* __restrict__ mi,
                                                 const float* __restrict__ h1,
                                                 float* __restrict__ out) {
    int wave = threadIdx.x >> 6, lane = threadIdx.x & 63;
    int row = blockIdx.x * 4 + wave;
    const f4* w4 = (const f4*)(Wd + (size_t)row * II);
    const f4* x4 = (const f4*)mi;
    float acc = 0.f;
    for (int o = 0; o < 3; o++) {  // bounded unroll: <=16 loads in flight
#pragma unroll
        for (int ii = 0; ii < 16; ii++) {
            int i = lane + (o * 16 + ii) * 64;
            f4 a = ntload(w4 + i);
            f4 b = x4[i];
            acc += a.x * b.x + a.y * b.y + a.z * b.z + a.w * b.w;
        }
    }
    acc = wave_reduce_sum(acc);
    if (lane == 0) out[row] = h1[row] + acc;
}

extern "C" void kernel_launch(void* const* d_in, const int* in_sizes, int n_in,
                              void* d_out, int out_size, void* d_ws, size_t ws_size,
                              hipStream_t stream) {
    const float* x        = (const float*)d_in[0];   // hidden_conv (4096)
    const float* position = (const float*)d_in[1];
    const float* cosv     = (const float*)d_in[2];
    const float* sinv     = (const float*)d_in[3];
    const float* k_cache  = (const float*)d_in[4];
    const float* v_cache  = (const float*)d_in[5];
    const float* Wq       = (const float*)d_in[6];
    const float* Wk       = (const float*)d_in[7];
    const float* Wv       = (const float*)d_in[8];
    const float* Wo       = (const float*)d_in[9];
    const float* Wg       = (const float*)d_in[10];
    const float* Wu       = (const float*)d_in[11];
    const float* Wd       = (const float*)d_in[12];
    const float* q_norm_w = (const float*)d_in[13];
    const float* k_norm_w = (const float*)d_in[14];
    const float* ln1_w    = (const float*)d_in[15];
    const float* ln2_w    = (const float*)d_in[16];

    float* out_hid = (float*)d_out;
    float* out_k   = out_hid + HID;
    float* out_v   = out_k + (size_t)HKV * SS * DD;

    float* ws = (float*)d_ws;
    float* q        = ws;                  // 4096 (raw, un-roped)
    float* k        = q + H * DD;          // 1024 (raw)
    float* v        = k + HKV * DD;        // 1024
    float* attn_out = v + HKV * DD;        // 4096
    float* h1       = attn_out + H * DD;   // 4096
    float* mi       = h1 + HID;            // 12288
    float* part_m   = mi + II;             // 1024
    float* part_l   = part_m + H * NC;     // 1024
    float* part_o   = part_l + H * NC;     // 131072

    front<<<5632, 256, 0, stream>>>(Wq, Wk, Wv, x, ln1_w, k_cache, v_cache,
                                    q, k, v, out_k, out_v);
    attn_partial<<<dim3(H, NC), 256, 0, stream>>>(q, k, v, out_k, out_v,
                                                  cosv, sinv, q_norm_w, k_norm_w,
                                                  position, part_m, part_l, part_o);
    attn_combine<<<H, 128, 0, stream>>>(part_m, part_l, part_o, attn_out);
    gemv_wo<<<1024, 256, 0, stream>>>(Wo, attn_out, x, h1);
    gemv_gateup<<<3072, 256, 0, stream>>>(Wg, Wu, h1, ln2_w, mi);
    gemv_down<<<1024, 256, 0, stream>>>(Wd, mi, h1, out_hid);
}